// Round 6
// baseline (100.997 us; speedup 1.0000x reference)
//
#include <hip/hip_runtime.h>
#include <hip/hip_bf16.h>

#define N_NODES 8192
#define IN_F 128
#define OUT_F 64
#define ALPHA 0.2f
#define CAP 512  // per-wave edge cap (expected ~164, max ~230 for p=0.02)
#define WT_STRIDE 132  // 16B-aligned lane rows for ds_read_b128

// Kernel 1: h = x @ W  [N,64];  hi = h @ a[:64];  hj = h @ a[64:]
// 1024 blocks x 256 threads; each wave computes 2 rows (lane = out feature).
__global__ __launch_bounds__(256, 4) void gat_h(
    const float* __restrict__ x, const float* __restrict__ W,
    const float* __restrict__ a, float* __restrict__ h,
    float* __restrict__ hi, float* __restrict__ hj) {
  __shared__ float sWt[OUT_F][WT_STRIDE];  // sWt[f][k] = W[k][f], 33 KB
  int tid = threadIdx.x;
  for (int i = tid; i < IN_F * OUT_F; i += 256) {
    int k = i >> 6, f = i & 63;
    sWt[f][k] = W[i];
  }
  __syncthreads();

  int lane = tid & 63;
  int wid = tid >> 6;
  float a1 = a[lane], a2 = a[OUT_F + lane];
  int row0 = blockIdx.x * 8;

  for (int rr = 0; rr < 2; ++rr) {
    int row = row0 + rr * 4 + wid;
    const float4* xr = (const float4*)(x + (size_t)row * IN_F);
    float acc = 0.f;
#pragma unroll
    for (int k4 = 0; k4 < IN_F / 4; ++k4) {
      float4 xv = xr[k4];  // wave-uniform broadcast load
      float4 wv = *(const float4*)&sWt[lane][k4 * 4];  // aligned ds_read_b128
      acc = fmaf(xv.x, wv.x, acc);
      acc = fmaf(xv.y, wv.y, acc);
      acc = fmaf(xv.z, wv.z, acc);
      acc = fmaf(xv.w, wv.w, acc);
    }
    h[(size_t)row * 64 + lane] = acc;
    float vi = acc * a1, vj = acc * a2;
#pragma unroll
    for (int o = 32; o >= 1; o >>= 1) {
      vi += __shfl_xor(vi, o);
      vj += __shfl_xor(vj, o);
    }
    if (lane == 0) { hi[row] = vi; hj[row] = vj; }
  }
}

// Kernel 2: ONE WAVE per row, ZERO barriers.
// Full row scan = 32 float4/lane (R3-R5 bug: only 8 -> quarter of the row).
// 128-bit predicate mask per lane held as 4 x u32 words.
__global__ __launch_bounds__(256, 4) void gat_row(
    const float* __restrict__ adj, const float* __restrict__ h,
    const float* __restrict__ hi, const float* __restrict__ hj,
    float* __restrict__ out) {
  __shared__ int s_idx[4][CAP];
  __shared__ float s_w[4][CAP];

  int tid = threadIdx.x;
  int lane = tid & 63;
  int wid = tid >> 6;
  int row = blockIdx.x * 4 + wid;

  // --- adj row -> 128-bit mask per lane (32 float4 loads, pipelined) ---
  const float4* arow = (const float4*)(adj + (size_t)row * N_NODES);
  unsigned int mask[4];
#pragma unroll
  for (int g = 0; g < 4; ++g) {
    unsigned int mk = 0;
#pragma unroll
    for (int it = 0; it < 8; ++it) {
      float4 vv = arow[lane + (g * 8 + it) * 64];
      mk |= (unsigned int)(vv.x > 0.f) << (it * 4 + 0);
      mk |= (unsigned int)(vv.y > 0.f) << (it * 4 + 1);
      mk |= (unsigned int)(vv.z > 0.f) << (it * 4 + 2);
      mk |= (unsigned int)(vv.w > 0.f) << (it * 4 + 3);
    }
    mask[g] = mk;
  }
  int c = __popc(mask[0]) + __popc(mask[1]) + __popc(mask[2]) + __popc(mask[3]);

  // --- wave inclusive prefix sum ---
  int incl = c;
#pragma unroll
  for (int o = 1; o < 64; o <<= 1) {
    int t = __shfl_up(incl, o);
    if (lane >= o) incl += t;
  }
  int off = incl - c;                 // exclusive prefix within wave
  int cnt = __shfl(incl, 63);         // wave total

  // --- place edges via ctz, leaky-relu logits, local max ---
  int* widx = s_idx[wid];
  float* ww = s_w[wid];
  float hii = hi[row];
  float lmax = -1e30f;
#pragma unroll
  for (int g = 0; g < 4; ++g) {
    unsigned int m = mask[g];
    while (m) {
      int b = __ffs(m) - 1;  // bit = it*4 + comp, it local to group g
      m &= m - 1;
      // column j = 4*(lane + (g*8 + (b>>2))*64) + (b&3)
      int j = ((lane + ((g * 8 + (b >> 2)) << 6)) << 2) + (b & 3);
      float l = hii + hj[j];
      l = (l > 0.f) ? l : ALPHA * l;
      if (off < CAP) { widx[off] = j; ww[off] = l; }
      ++off;
      lmax = fmaxf(lmax, l);
    }
  }

  // --- wave max ---
#pragma unroll
  for (int o = 32; o >= 1; o >>= 1) lmax = fmaxf(lmax, __shfl_xor(lmax, o));
  if (cnt > CAP) cnt = CAP;
  int cnt_pad = (cnt + 7) & ~7;

  // --- exp + wave sum; zero-pad tail for branch-free gather ---
  float lsum = 0.f;
  for (int e = lane; e < cnt; e += 64) {
    float w = __expf(ww[e] - lmax);
    ww[e] = w;
    lsum += w;
  }
  if (cnt + lane < cnt_pad) { ww[cnt + lane] = 0.f; widx[cnt + lane] = 0; }
#pragma unroll
  for (int o = 32; o >= 1; o >>= 1) lsum += __shfl_xor(lsum, o);
  float inv = 1.f / lsum;

  // --- weighted gather of h: 8 accumulators, wave-uniform LDS quads ---
  float acc0 = 0.f, acc1 = 0.f, acc2 = 0.f, acc3 = 0.f;
  float acc4 = 0.f, acc5 = 0.f, acc6 = 0.f, acc7 = 0.f;
  for (int e = 0; e < cnt_pad; e += 8) {
    int4 ia = *(const int4*)&widx[e];
    int4 ib = *(const int4*)&widx[e + 4];
    float4 wa = *(const float4*)&ww[e];
    float4 wb = *(const float4*)&ww[e + 4];
    acc0 = fmaf(wa.x, h[(size_t)ia.x * 64 + lane], acc0);
    acc1 = fmaf(wa.y, h[(size_t)ia.y * 64 + lane], acc1);
    acc2 = fmaf(wa.z, h[(size_t)ia.z * 64 + lane], acc2);
    acc3 = fmaf(wa.w, h[(size_t)ia.w * 64 + lane], acc3);
    acc4 = fmaf(wb.x, h[(size_t)ib.x * 64 + lane], acc4);
    acc5 = fmaf(wb.y, h[(size_t)ib.y * 64 + lane], acc5);
    acc6 = fmaf(wb.z, h[(size_t)ib.z * 64 + lane], acc6);
    acc7 = fmaf(wb.w, h[(size_t)ib.w * 64 + lane], acc7);
  }
  float vv = ((acc0 + acc1) + (acc2 + acc3)) + ((acc4 + acc5) + (acc6 + acc7));
  vv *= inv;
  vv = (vv > 0.f) ? vv : expm1f(vv);  // ELU
  out[(size_t)row * 64 + lane] = vv;
}

extern "C" void kernel_launch(void* const* d_in, const int* in_sizes, int n_in,
                              void* d_out, int out_size, void* d_ws, size_t ws_size,
                              hipStream_t stream) {
  const float* x   = (const float*)d_in[0];  // [8192,128]
  const float* adj = (const float*)d_in[1];  // [8192,8192]
  const float* W   = (const float*)d_in[2];  // [128,64]
  const float* a   = (const float*)d_in[3];  // [128,1]
  float* out = (float*)d_out;                // [8192,64]

  float* h  = (float*)d_ws;                  // 8192*64
  float* hi = h + (size_t)N_NODES * OUT_F;   // 8192
  float* hj = hi + N_NODES;                  // 8192

  gat_h<<<N_NODES / 8, 256, 0, stream>>>(x, W, a, h, hi, hj);
  gat_row<<<N_NODES / 4, 256, 0, stream>>>(adj, h, hi, hj, out);
}